// Round 16
// baseline (634.005 us; speedup 1.0000x reference)
//
#include <hip/hip_runtime.h>

#define NG 1024
#define GN_EPS 1e-5f
#define BSHIFT 7  // 128 nodes per bucket

typedef unsigned int u32;
typedef float f32x2 __attribute__((ext_vector_type(2)));

__device__ __forceinline__ float bflo(u32 u) {
  union { float f; u32 i; } c;
  c.i = u << 16;
  return c.f;
}
__device__ __forceinline__ float bfhi(u32 u) {
  union { float f; u32 i; } c;
  c.i = u & 0xffff0000u;
  return c.f;
}
__device__ __forceinline__ unsigned short f2bf(float f) {
  union { float f; u32 i; } c;
  c.f = f;
  u32 b = c.i;
  b += 0x7fffu + ((b >> 16) & 1u);  // RNE
  return (unsigned short)(b >> 16);
}
// packed accumulate: per u32 pair {lshl, and, v_pk_add_f32} -- exact f32 adds
__device__ __forceinline__ void acc8(f32x2* a, uint4 u) {
  a[0] += (f32x2){bflo(u.x), bfhi(u.x)};
  a[1] += (f32x2){bflo(u.y), bfhi(u.y)};
  a[2] += (f32x2){bflo(u.z), bfhi(u.z)};
  a[3] += (f32x2){bflo(u.w), bfhi(u.w)};
}

// ---------------- graph boundaries from sorted batch ----------------
__global__ void k_bounds(const int* __restrict__ batch, int* __restrict__ goff, int N) {
  int i = blockIdx.x * blockDim.x + threadIdx.x;
  if (i >= N) return;
  int b = batch[i];
  int pb = (i == 0) ? -1 : batch[i - 1];
  for (int g = pb + 1; g <= b; ++g) goff[g] = i;
  if (i == N - 1) {
    for (int g = b + 1; g <= NG; ++g) goff[g] = N;
  }
}

// ---------------- bucketed CSR build ----------------
__global__ void k_hist(const int* __restrict__ dst, int* __restrict__ bucketCnt,
                       int E, int B) {
  __shared__ int h[1024];
  for (int i = threadIdx.x; i < B; i += 256) h[i] = 0;
  __syncthreads();
  for (int e = blockIdx.x * 256 + threadIdx.x; e < E; e += gridDim.x * 256)
    atomicAdd(&h[dst[e] >> BSHIFT], 1);
  __syncthreads();
  for (int i = threadIdx.x; i < B; i += 256)
    if (h[i]) atomicAdd(&bucketCnt[i], h[i]);
}

__global__ void k_bscan(const int* __restrict__ bucketCnt, int* __restrict__ bucketOff,
                        int* __restrict__ bucketCur, int B) {
  __shared__ int lds[1024];
  int t = threadIdx.x;
  int v = (t < B) ? bucketCnt[t] : 0;
  lds[t] = v;
  __syncthreads();
  for (int off = 1; off < 1024; off <<= 1) {
    int u = (t >= off) ? lds[t - off] : 0;
    __syncthreads();
    lds[t] += u;
    __syncthreads();
  }
  if (t < B) {
    int ex = lds[t] - v;
    bucketOff[t] = ex;
    bucketCur[t] = ex;
  }
}

__global__ __launch_bounds__(256) void k_binscatter(
    const int* __restrict__ src, const int* __restrict__ dst,
    int* __restrict__ bucketCur, u32* __restrict__ ebuf,
    int E, int B, int C) {
  __shared__ int h[1024];
  __shared__ int cur[1024];
  int s = blockIdx.x * C;
  int e = min(s + C, E);
  if (s >= E) return;
  int t = threadIdx.x;
  for (int i = t; i < B; i += 256) h[i] = 0;
  __syncthreads();
  for (int k = s + t; k < e; k += 256) atomicAdd(&h[dst[k] >> BSHIFT], 1);
  __syncthreads();
  for (int i = t; i < B; i += 256) {
    int c = h[i];
    cur[i] = c ? atomicAdd(&bucketCur[i], c) : 0;
  }
  __syncthreads();
  for (int k = s + t; k < e; k += 256) {
    int d = dst[k];
    int b = d >> BSHIFT;
    int pos = atomicAdd(&cur[b], 1);
    ebuf[pos] = ((u32)(d & 127) << 24) | (u32)src[k];
  }
}

// per-(row,strip) CSR: srow[n*4+s] = start of strip s of row n; strip = src>>15.
// Row n spans [srow[4n], srow[4n+4]); contiguous across rows and buckets.
__global__ void k_bucket_fill(const u32* __restrict__ ebuf,
                              const int* __restrict__ bucketOff,
                              int* __restrict__ srow, int* __restrict__ col,
                              int N, int E, int B) {
  __shared__ int deg[512];  // [dloc][strip]
  __shared__ int cur[512];
  int b = blockIdx.x;
  int s = bucketOff[b];
  int e = (b + 1 < B) ? bucketOff[b + 1] : E;
  int t = threadIdx.x;
  int base = b << BSHIFT;
  for (int i = t; i < 512; i += 256) deg[i] = 0;
  __syncthreads();
  for (int k = s + t; k < e; k += 256) {
    u32 p = ebuf[k];
    atomicAdd(&deg[(p >> 24) * 4 + ((p & 0xffffffu) >> 15)], 1);
  }
  __syncthreads();
  if (t == 0) {
    int acc = s;
    for (int i = 0; i < 512; ++i) {
      int d = deg[i];
      deg[i] = acc;
      acc += d;
    }
  }
  __syncthreads();
  for (int i = t; i < 512; i += 256) cur[i] = deg[i];
  if (t < 128) {
    int idx = base + t;
    if (idx < N) {
#pragma unroll
      for (int q = 0; q < 4; ++q) srow[idx * 4 + q] = deg[t * 4 + q];
    }
  }
  if (b == B - 1 && t == 0) srow[4 * N] = E;
  __syncthreads();
  for (int k = s + t; k < e; k += 256) {
    u32 p = ebuf[k];
    int sv = (int)(p & 0xffffffu);
    int pos = atomicAdd(&cur[(p >> 24) * 4 + (sv >> 15)], 1);
    col[pos] = sv;
  }
}

// ---------------- GraphNorm: f32 in -> f32 out + bf16 mirror (gather operand) ----------------
template <int F>
__global__ void k_gn(const float* x, float* out, unsigned short* outbf,
                     const int* __restrict__ goff,
                     const float* __restrict__ w, const float* __restrict__ b,
                     const float* __restrict__ ms) {
  constexpr int NPW = 256 / F;
  __shared__ float r1[256], r2[256];
  __shared__ float sA[F], sB[F];
  int g = blockIdx.x;
  int s = goff[g], e = goff[g + 1];
  int t = threadIdx.x;
  int f = t % F, sub = t / F;
  float s1 = 0.f, s2 = 0.f;
  for (int i = s + sub; i < e; i += NPW) {
    float v = x[i * F + f];
    s1 += v;
    s2 += v * v;
  }
  r1[t] = s1;
  r2[t] = s2;
  __syncthreads();
  if (t < F) {
    float S1 = 0.f, S2 = 0.f;
    for (int k = 0; k < NPW; ++k) {
      S1 += r1[k * F + t];
      S2 += r2[k * F + t];
    }
    float cnt = (float)max(e - s, 1);
    float mean = S1 / cnt, m2 = S2 / cnt;
    float m = ms[t];
    float var = m2 + mean * mean * m * (m - 2.f);  // E[(x-mean*ms)^2]
    float rsq = rsqrtf(var + GN_EPS);
    float Av = w[t] * rsq;
    sA[t] = Av;
    sB[t] = b[t] - mean * m * Av;
  }
  __syncthreads();
  float Af = sA[f], Bf = sB[f];
  for (int i = s + sub; i < e; i += NPW) {
    float v = x[i * F + f] * Af + Bf;
    out[i * F + f] = v;
    outbf[i * F + f] = f2bf(v);
  }
}

// ---------------- GraphConv (R15 structure + src-strip blocked gather) ----------------
// block = 256 (4 waves), tile = 64 nodes; wave w owns rows [16w,16w+16).
// lane = (slot, fg): FIN=64: 8 slots x 8 fg (uint4 = 8 bf16 = 16B/lane);
// FIN=16: 32 slots x 2 fg. Rows in PAIRS with dual accumulators -> 4 uint4
// streams in flight. FIN=64 iterates 4 src-strips (each <=4MB of mirror,
// L2-resident while all concurrent blocks process the same strip); FIN=16's
// mirror is 3.2MB (L2-fit) -> single pass. Butterfly reduce starts at FGN.
// Matvec: lane = node, wave w computes 16 output feats.
template <int FIN>
__global__ __launch_bounds__(256) void k_conv(
    const float* __restrict__ hin, const u32* __restrict__ hb32,
    float* __restrict__ hout,
    const int* __restrict__ srow, const int* __restrict__ col,
    const float* __restrict__ wrel, const float* __restrict__ brel,
    const float* __restrict__ wroot, int N) {
  constexpr int PAD = FIN + 4;
  constexpr int CPR = FIN / 2;              // u32 per node row in mirror
  constexpr int FGN = (FIN == 64) ? 8 : 2;  // fg lanes per row (8 feats each)
  constexpr int NSLOT = 64 / FGN;           // neighbor slots per row
  __shared__ float aggL[64 * PAD];
  int tile = blockIdx.x;
  int lane = threadIdx.x & 63;
  int w = __builtin_amdgcn_readfirstlane(threadIdx.x >> 6);

  int fg = lane & (FGN - 1);
  int slot = lane / FGN;

  for (int nl = 0; nl < 16; nl += 2) {
    int r0 = w * 16 + nl, r1 = r0 + 1;
    int n0 = tile * 64 + r0, n1 = tile * 64 + r1;
    f32x2 a0[4], b0[4], a1[4], b1[4];
#pragma unroll
    for (int j = 0; j < 4; ++j) {
      a0[j] = (f32x2){0.f, 0.f};
      b0[j] = (f32x2){0.f, 0.f};
      a1[j] = (f32x2){0.f, 0.f};
      b1[j] = (f32x2){0.f, 0.f};
    }
    // strip bounds: sr[q]..sr[q+1] for q=0..3 (sr[4] = row end)
    int sr0[5], sr1[5];
    if (n0 < N) {
      int4 q4 = *(const int4*)&srow[4 * n0];
      sr0[0] = q4.x; sr0[1] = q4.y; sr0[2] = q4.z; sr0[3] = q4.w;
      sr0[4] = srow[4 * n0 + 4];
    } else {
#pragma unroll
      for (int q = 0; q < 5; ++q) sr0[q] = 0;
    }
    if (n1 < N) {
      int4 q4 = *(const int4*)&srow[4 * n1];
      sr1[0] = q4.x; sr1[1] = q4.y; sr1[2] = q4.z; sr1[3] = q4.w;
      sr1[4] = srow[4 * n1 + 4];
    } else {
#pragma unroll
      for (int q = 0; q < 5; ++q) sr1[q] = 0;
    }

    auto gpair = [&](int k0, int e0, int k1, int e1) {
      k0 += slot;
      k1 += slot;
      while (k0 + NSLOT < e0 && k1 + NSLOT < e1) {
        int nb00 = col[k0];
        int nb01 = col[k0 + NSLOT];
        int nb10 = col[k1];
        int nb11 = col[k1 + NSLOT];
        uint4 v00 = *(const uint4*)&hb32[(size_t)nb00 * CPR + fg * 4];
        uint4 v01 = *(const uint4*)&hb32[(size_t)nb01 * CPR + fg * 4];
        uint4 v10 = *(const uint4*)&hb32[(size_t)nb10 * CPR + fg * 4];
        uint4 v11 = *(const uint4*)&hb32[(size_t)nb11 * CPR + fg * 4];
        acc8(a0, v00);
        acc8(b0, v01);
        acc8(a1, v10);
        acc8(b1, v11);
        k0 += 2 * NSLOT;
        k1 += 2 * NSLOT;
      }
      for (; k0 + NSLOT < e0; k0 += 2 * NSLOT) {
        int nb0 = col[k0];
        int nb1 = col[k0 + NSLOT];
        uint4 v0 = *(const uint4*)&hb32[(size_t)nb0 * CPR + fg * 4];
        uint4 v1 = *(const uint4*)&hb32[(size_t)nb1 * CPR + fg * 4];
        acc8(a0, v0);
        acc8(b0, v1);
      }
      if (k0 < e0) {
        int nb = col[k0];
        uint4 v = *(const uint4*)&hb32[(size_t)nb * CPR + fg * 4];
        acc8(a0, v);
      }
      for (; k1 + NSLOT < e1; k1 += 2 * NSLOT) {
        int nb0 = col[k1];
        int nb1 = col[k1 + NSLOT];
        uint4 v0 = *(const uint4*)&hb32[(size_t)nb0 * CPR + fg * 4];
        uint4 v1 = *(const uint4*)&hb32[(size_t)nb1 * CPR + fg * 4];
        acc8(a1, v0);
        acc8(b1, v1);
      }
      if (k1 < e1) {
        int nb = col[k1];
        uint4 v = *(const uint4*)&hb32[(size_t)nb * CPR + fg * 4];
        acc8(a1, v);
      }
    };

    if (FIN == 64) {
#pragma unroll
      for (int q = 0; q < 4; ++q) gpair(sr0[q], sr0[q + 1], sr1[q], sr1[q + 1]);
    } else {
      gpair(sr0[0], sr0[4], sr1[0], sr1[4]);
    }

#pragma unroll
    for (int j = 0; j < 4; ++j) { a0[j] += b0[j]; a1[j] += b1[j]; }
    // reduce across neighbor slots: masks FGN, 2*FGN, ..., 32
#pragma unroll
    for (int m = FGN; m < 64; m <<= 1) {
#pragma unroll
      for (int j = 0; j < 4; ++j) {
        a0[j][0] += __shfl_xor(a0[j][0], m);
        a0[j][1] += __shfl_xor(a0[j][1], m);
        a1[j][0] += __shfl_xor(a1[j][0], m);
        a1[j][1] += __shfl_xor(a1[j][1], m);
      }
    }
    if (slot == 0) {
      *(float4*)&aggL[r0 * PAD + fg * 8] =
          make_float4(a0[0][0], a0[0][1], a0[1][0], a0[1][1]);
      *(float4*)&aggL[r0 * PAD + fg * 8 + 4] =
          make_float4(a0[2][0], a0[2][1], a0[3][0], a0[3][1]);
      *(float4*)&aggL[r1 * PAD + fg * 8] =
          make_float4(a1[0][0], a1[0][1], a1[1][0], a1[1][1]);
      *(float4*)&aggL[r1 * PAD + fg * 8 + 4] =
          make_float4(a1[2][0], a1[2][1], a1[3][0], a1[3][1]);
    }
  }
  __syncthreads();

  int n = tile * 64 + lane;
  if (n >= N) return;
  int wbase = w * 16;
  float accR[16], accT[16];
#pragma unroll
  for (int j = 0; j < 16; ++j) {
    accR[j] = 0.f;
    accT[j] = 0.f;
  }
#pragma unroll 2
  for (int fq = 0; fq < FIN / 4; ++fq) {
    float4 qa = *(const float4*)&aggL[lane * PAD + fq * 4];
    float4 qh = *(const float4*)&hin[(size_t)n * FIN + fq * 4];
#pragma unroll
    for (int j = 0; j < 16; ++j) {
      int o = wbase + j;
      const float* wr = &wrel[o * FIN + fq * 4];
      const float* wt = &wroot[o * FIN + fq * 4];
      accR[j] += wr[0] * qa.x + wr[1] * qa.y + wr[2] * qa.z + wr[3] * qa.w;
      accT[j] += wt[0] * qh.x + wt[1] * qh.y + wt[2] * qh.z + wt[3] * qh.w;
    }
  }
#pragma unroll
  for (int qq = 0; qq < 4; ++qq) {
    float4 rv;
    float* rr = (float*)&rv;
#pragma unroll
    for (int jj = 0; jj < 4; ++jj) {
      int j = qq * 4 + jj;
      rr[jj] = fmaxf(accR[j] + accT[j] + brel[wbase + j], 0.f);
    }
    *(float4*)&hout[(size_t)n * 64 + wbase + qq * 4] = rv;
  }
}

// ---------------- mean-pool + dense(relu) + out + softmax ----------------
__global__ void k_final(const float* __restrict__ h, const int* __restrict__ goff,
                        const float* __restrict__ dw, const float* __restrict__ db,
                        const float* __restrict__ ow, const float* __restrict__ ob,
                        float* __restrict__ out) {
  __shared__ float red[256];
  __shared__ float pl[64];
  __shared__ float gl[64];
  int g = blockIdx.x;
  int s = goff[g], e = goff[g + 1];
  int t = threadIdx.x;
  int f = t & 63, sub = t >> 6;
  float s1 = 0.f;
  for (int i = s + sub; i < e; i += 4) s1 += h[i * 64 + f];
  red[t] = s1;
  __syncthreads();
  if (t < 64) {
    float S = red[t] + red[64 + t] + red[128 + t] + red[192 + t];
    float cnt = (float)max(e - s, 1);
    pl[t] = S / cnt;
  }
  __syncthreads();
  if (t < 64) {
    float acc = db[t];
#pragma unroll 8
    for (int k = 0; k < 64; ++k) acc += dw[t * 64 + k] * pl[k];
    gl[t] = fmaxf(acc, 0.f);
  }
  __syncthreads();
  if (t == 0) {
    float l0 = ob[0], l1 = ob[1];
    for (int k = 0; k < 64; ++k) {
      l0 += ow[k] * gl[k];
      l1 += ow[64 + k] * gl[k];
    }
    float m = fmaxf(l0, l1);
    float e0 = expf(l0 - m), e1 = expf(l1 - m);
    float inv = 1.f / (e0 + e1);
    out[g * 2 + 0] = e0 * inv;
    out[g * 2 + 1] = e1 * inv;
  }
}

extern "C" void kernel_launch(void* const* d_in, const int* in_sizes, int n_in,
                              void* d_out, int out_size, void* d_ws, size_t ws_size,
                              hipStream_t stream) {
  const float* x = (const float*)d_in[0];
  const int* ei = (const int*)d_in[1];
  const int* batch = (const int*)d_in[2];
  const float* gn0_w = (const float*)d_in[3];
  const float* gn0_b = (const float*)d_in[4];
  const float* gn0_ms = (const float*)d_in[5];
  const float* gn1_w = (const float*)d_in[6];
  const float* gn1_b = (const float*)d_in[7];
  const float* gn1_ms = (const float*)d_in[8];
  const float* gn2_w = (const float*)d_in[9];
  const float* gn2_b = (const float*)d_in[10];
  const float* gn2_ms = (const float*)d_in[11];
  const float* w1_rel = (const float*)d_in[12];
  const float* b1 = (const float*)d_in[13];
  const float* w1_root = (const float*)d_in[14];
  const float* w2_rel = (const float*)d_in[15];
  const float* b2 = (const float*)d_in[16];
  const float* w2_root = (const float*)d_in[17];
  const float* w3_rel = (const float*)d_in[18];
  const float* b3 = (const float*)d_in[19];
  const float* w3_root = (const float*)d_in[20];
  const float* dense_w = (const float*)d_in[21];
  const float* dense_b = (const float*)d_in[22];
  const float* out_w = (const float*)d_in[23];
  const float* out_b = (const float*)d_in[24];

  int N = in_sizes[2];
  int E = in_sizes[1] / 2;
  int B = (N >> BSHIFT) + 1;

  char* ws = (char*)d_ws;
  auto alloc = [&](size_t bytes) {
    char* p = ws;
    ws += (bytes + 255) & ~(size_t)255;
    return p;
  };
  int* srow = (int*)alloc(((size_t)N * 4 + 1) * 4);
  int* goff = (int*)alloc((NG + 1) * 4);
  int* bucketCnt = (int*)alloc((size_t)B * 4);
  int* bucketOff = (int*)alloc((size_t)B * 4);
  int* bucketCur = (int*)alloc((size_t)B * 4);
  int* col = (int*)alloc((size_t)E * 4);
  size_t hbytes = (size_t)N * 64 * 4;
  size_t ebytes = (size_t)E * 4;  // u32 entries
  char* hA_raw = (char*)alloc(hbytes > ebytes ? hbytes : ebytes);  // hA aliases ebuf
  float* hA = (float*)hA_raw;
  u32* ebuf = (u32*)hA_raw;
  float* hB = (float*)alloc(hbytes);
  unsigned short* hbf = (unsigned short*)alloc((size_t)N * 64 * 2);

  const int* src = ei;
  const int* dst = ei + E;

  hipMemsetAsync(bucketCnt, 0, (size_t)B * 4, stream);
  k_bounds<<<(N + 255) / 256, 256, 0, stream>>>(batch, goff, N);
  k_hist<<<256, 256, 0, stream>>>(dst, bucketCnt, E, B);
  k_bscan<<<1, 1024, 0, stream>>>(bucketCnt, bucketOff, bucketCur, B);
  int nbs = 192;
  int C = (E + nbs - 1) / nbs;
  k_binscatter<<<nbs, 256, 0, stream>>>(src, dst, bucketCur, ebuf, E, B, C);
  k_bucket_fill<<<B, 256, 0, stream>>>(ebuf, bucketOff, srow, col, N, E, B);

  int tiles = (N + 63) / 64;
  k_gn<16><<<NG, 256, 0, stream>>>(x, hA, hbf, goff, gn0_w, gn0_b, gn0_ms);
  k_conv<16><<<tiles, 256, 0, stream>>>(hA, (const u32*)hbf, hB, srow, col, w1_rel, b1, w1_root, N);
  k_gn<64><<<NG, 256, 0, stream>>>(hB, hB, hbf, goff, gn1_w, gn1_b, gn1_ms);
  k_conv<64><<<tiles, 256, 0, stream>>>(hB, (const u32*)hbf, hA, srow, col, w2_rel, b2, w2_root, N);
  k_gn<64><<<NG, 256, 0, stream>>>(hA, hA, hbf, goff, gn2_w, gn2_b, gn2_ms);
  k_conv<64><<<tiles, 256, 0, stream>>>(hA, (const u32*)hbf, hB, srow, col, w3_rel, b3, w3_root, N);
  k_final<<<NG, 256, 0, stream>>>(hB, goff, dense_w, dense_b, out_w, out_b, (float*)d_out);
}

// Round 18
// 505.902 us; speedup vs baseline: 1.2532x; 1.2532x over previous
//
#include <hip/hip_runtime.h>

#define NG 1024
#define GN_EPS 1e-5f
#define BSHIFT 7  // 128 nodes per bucket

typedef unsigned int u32;
typedef float f32x2 __attribute__((ext_vector_type(2)));

__device__ __forceinline__ float bflo(u32 u) {
  union { float f; u32 i; } c;
  c.i = u << 16;
  return c.f;
}
__device__ __forceinline__ float bfhi(u32 u) {
  union { float f; u32 i; } c;
  c.i = u & 0xffff0000u;
  return c.f;
}
__device__ __forceinline__ unsigned short f2bf(float f) {
  union { float f; u32 i; } c;
  c.f = f;
  u32 b = c.i;
  b += 0x7fffu + ((b >> 16) & 1u);  // RNE
  return (unsigned short)(b >> 16);
}
// packed accumulate: per u32 pair {lshl, and, v_pk_add_f32} -- exact f32 adds
__device__ __forceinline__ void acc8(f32x2* a, uint4 u) {
  a[0] += (f32x2){bflo(u.x), bfhi(u.x)};
  a[1] += (f32x2){bflo(u.y), bfhi(u.y)};
  a[2] += (f32x2){bflo(u.z), bfhi(u.z)};
  a[3] += (f32x2){bflo(u.w), bfhi(u.w)};
}

// ---------------- graph boundaries from sorted batch ----------------
__global__ void k_bounds(const int* __restrict__ batch, int* __restrict__ goff, int N) {
  int i = blockIdx.x * blockDim.x + threadIdx.x;
  if (i >= N) return;
  int b = batch[i];
  int pb = (i == 0) ? -1 : batch[i - 1];
  for (int g = pb + 1; g <= b; ++g) goff[g] = i;
  if (i == N - 1) {
    for (int g = b + 1; g <= NG; ++g) goff[g] = N;
  }
}

// ---------------- bucketed CSR build (R4-proven) ----------------
__global__ void k_hist(const int* __restrict__ dst, int* __restrict__ bucketCnt,
                       int E, int B) {
  __shared__ int h[1024];
  for (int i = threadIdx.x; i < B; i += 256) h[i] = 0;
  __syncthreads();
  for (int e = blockIdx.x * 256 + threadIdx.x; e < E; e += gridDim.x * 256)
    atomicAdd(&h[dst[e] >> BSHIFT], 1);
  __syncthreads();
  for (int i = threadIdx.x; i < B; i += 256)
    if (h[i]) atomicAdd(&bucketCnt[i], h[i]);
}

__global__ void k_bscan(const int* __restrict__ bucketCnt, int* __restrict__ bucketOff,
                        int* __restrict__ bucketCur, int B) {
  __shared__ int lds[1024];
  int t = threadIdx.x;
  int v = (t < B) ? bucketCnt[t] : 0;
  lds[t] = v;
  __syncthreads();
  for (int off = 1; off < 1024; off <<= 1) {
    int u = (t >= off) ? lds[t - off] : 0;
    __syncthreads();
    lds[t] += u;
    __syncthreads();
  }
  if (t < B) {
    int ex = lds[t] - v;
    bucketOff[t] = ex;
    bucketCur[t] = ex;
  }
}

__global__ __launch_bounds__(256) void k_binscatter(
    const int* __restrict__ src, const int* __restrict__ dst,
    int* __restrict__ bucketCur, u32* __restrict__ ebuf,
    int E, int B, int C) {
  __shared__ int h[1024];
  __shared__ int cur[1024];
  int s = blockIdx.x * C;
  int e = min(s + C, E);
  if (s >= E) return;
  int t = threadIdx.x;
  for (int i = t; i < B; i += 256) h[i] = 0;
  __syncthreads();
  for (int k = s + t; k < e; k += 256) atomicAdd(&h[dst[k] >> BSHIFT], 1);
  __syncthreads();
  for (int i = t; i < B; i += 256) {
    int c = h[i];
    cur[i] = c ? atomicAdd(&bucketCur[i], c) : 0;
  }
  __syncthreads();
  for (int k = s + t; k < e; k += 256) {
    int d = dst[k];
    int b = d >> BSHIFT;
    int pos = atomicAdd(&cur[b], 1);
    ebuf[pos] = ((u32)(d & 127) << 24) | (u32)src[k];
  }
}

__global__ void k_bucket_fill(const u32* __restrict__ ebuf,
                              const int* __restrict__ bucketOff,
                              int* __restrict__ rowptr, int* __restrict__ col,
                              int N, int E, int B) {
  __shared__ int deg[128];
  __shared__ int cur[128];
  int b = blockIdx.x;
  int s = bucketOff[b];
  int e = (b + 1 < B) ? bucketOff[b + 1] : E;
  int t = threadIdx.x;
  int base = b << BSHIFT;
  if (t < 128) deg[t] = 0;
  __syncthreads();
  for (int k = s + t; k < e; k += 256) atomicAdd(&deg[ebuf[k] >> 24], 1);
  __syncthreads();
  if (t == 0) {
    int acc = s;
    for (int i = 0; i < 128; ++i) {
      int d = deg[i];
      deg[i] = acc;
      acc += d;
    }
  }
  __syncthreads();
  if (t < 128) {
    cur[t] = deg[t];
    int idx = base + t;
    if (idx <= N) rowptr[idx] = deg[t];
  }
  __syncthreads();
  for (int k = s + t; k < e; k += 256) {
    u32 p = ebuf[k];
    int pos = atomicAdd(&cur[p >> 24], 1);
    col[pos] = (int)(p & 0x00ffffffu);
  }
}

// ---------------- GraphNorm: f32 in -> f32 out + bf16 mirror (gather operand) ----------------
template <int F>
__global__ void k_gn(const float* x, float* out, unsigned short* outbf,
                     const int* __restrict__ goff,
                     const float* __restrict__ w, const float* __restrict__ b,
                     const float* __restrict__ ms) {
  constexpr int NPW = 256 / F;
  __shared__ float r1[256], r2[256];
  __shared__ float sA[F], sB[F];
  int g = blockIdx.x;
  int s = goff[g], e = goff[g + 1];
  int t = threadIdx.x;
  int f = t % F, sub = t / F;
  float s1 = 0.f, s2 = 0.f;
  for (int i = s + sub; i < e; i += NPW) {
    float v = x[i * F + f];
    s1 += v;
    s2 += v * v;
  }
  r1[t] = s1;
  r2[t] = s2;
  __syncthreads();
  if (t < F) {
    float S1 = 0.f, S2 = 0.f;
    for (int k = 0; k < NPW; ++k) {
      S1 += r1[k * F + t];
      S2 += r2[k * F + t];
    }
    float cnt = (float)max(e - s, 1);
    float mean = S1 / cnt, m2 = S2 / cnt;
    float m = ms[t];
    float var = m2 + mean * mean * m * (m - 2.f);  // E[(x-mean*ms)^2]
    float rsq = rsqrtf(var + GN_EPS);
    float Av = w[t] * rsq;
    sA[t] = Av;
    sB[t] = b[t] - mean * m * Av;
  }
  __syncthreads();
  float Af = sA[f], Bf = sB[f];
  for (int i = s + sub; i < e; i += NPW) {
    float v = x[i * F + f] * Af + Bf;
    out[i * F + f] = v;
    outbf[i * F + f] = f2bf(v);
  }
}

// ---------------- GraphConv (R11 structure; packed-f32 accumulate) ----------------
// block = 256 (4 waves), tile = 64 nodes; wave w owns rows [16w,16w+16).
// lane = (slot, fg): FIN=64: 8 slots x 8 fg (uint4 = 8 bf16 = 16B/lane);
// FIN=16: 32 slots x 2 fg. Rows in PAIRS with dual accumulators -> 4 uint4
// streams in flight; butterfly reduce starts at FGN. Matvec: lane = node,
// wave w computes 16 output feats; agg from LDS, root from f32 hin.
template <int FIN>
__global__ __launch_bounds__(256) void k_conv(
    const float* __restrict__ hin, const u32* __restrict__ hb32,
    float* __restrict__ hout,
    const int* __restrict__ rowptr, const int* __restrict__ col,
    const float* __restrict__ wrel, const float* __restrict__ brel,
    const float* __restrict__ wroot, int N) {
  constexpr int PAD = FIN + 4;
  constexpr int CPR = FIN / 2;              // u32 per node row in mirror
  constexpr int FGN = (FIN == 64) ? 8 : 2;  // fg lanes per row (8 feats each)
  constexpr int NSLOT = 64 / FGN;           // neighbor slots per row
  __shared__ float aggL[64 * PAD];
  int tile = blockIdx.x;
  int lane = threadIdx.x & 63;
  int w = __builtin_amdgcn_readfirstlane(threadIdx.x >> 6);

  int fg = lane & (FGN - 1);
  int slot = lane / FGN;

  for (int nl = 0; nl < 16; nl += 2) {
    int r0 = w * 16 + nl, r1 = r0 + 1;
    int n0 = tile * 64 + r0, n1 = tile * 64 + r1;
    f32x2 a0[4], b0[4], a1[4], b1[4];
#pragma unroll
    for (int j = 0; j < 4; ++j) {
      a0[j] = (f32x2){0.f, 0.f};
      b0[j] = (f32x2){0.f, 0.f};
      a1[j] = (f32x2){0.f, 0.f};
      b1[j] = (f32x2){0.f, 0.f};
    }
    int k0 = 0, e0 = 0, k1 = 0, e1 = 0;
    if (n0 < N) { k0 = rowptr[n0] + slot; e0 = rowptr[n0 + 1]; }
    if (n1 < N) { k1 = rowptr[n1] + slot; e1 = rowptr[n1 + 1]; }
    // combined main loop: 4 independent 16B gather streams
    while (k0 + NSLOT < e0 && k1 + NSLOT < e1) {
      int nb00 = col[k0];
      int nb01 = col[k0 + NSLOT];
      int nb10 = col[k1];
      int nb11 = col[k1 + NSLOT];
      uint4 v00 = *(const uint4*)&hb32[(size_t)nb00 * CPR + fg * 4];
      uint4 v01 = *(const uint4*)&hb32[(size_t)nb01 * CPR + fg * 4];
      uint4 v10 = *(const uint4*)&hb32[(size_t)nb10 * CPR + fg * 4];
      uint4 v11 = *(const uint4*)&hb32[(size_t)nb11 * CPR + fg * 4];
      acc8(a0, v00);
      acc8(b0, v01);
      acc8(a1, v10);
      acc8(b1, v11);
      k0 += 2 * NSLOT;
      k1 += 2 * NSLOT;
    }
    // row0 tail
    for (; k0 + NSLOT < e0; k0 += 2 * NSLOT) {
      int nb0 = col[k0];
      int nb1 = col[k0 + NSLOT];
      uint4 v0 = *(const uint4*)&hb32[(size_t)nb0 * CPR + fg * 4];
      uint4 v1 = *(const uint4*)&hb32[(size_t)nb1 * CPR + fg * 4];
      acc8(a0, v0);
      acc8(b0, v1);
    }
    if (k0 < e0) {
      int nb = col[k0];
      uint4 v = *(const uint4*)&hb32[(size_t)nb * CPR + fg * 4];
      acc8(a0, v);
    }
    // row1 tail
    for (; k1 + NSLOT < e1; k1 += 2 * NSLOT) {
      int nb0 = col[k1];
      int nb1 = col[k1 + NSLOT];
      uint4 v0 = *(const uint4*)&hb32[(size_t)nb0 * CPR + fg * 4];
      uint4 v1 = *(const uint4*)&hb32[(size_t)nb1 * CPR + fg * 4];
      acc8(a1, v0);
      acc8(b1, v1);
    }
    if (k1 < e1) {
      int nb = col[k1];
      uint4 v = *(const uint4*)&hb32[(size_t)nb * CPR + fg * 4];
      acc8(a1, v);
    }
#pragma unroll
    for (int j = 0; j < 4; ++j) { a0[j] += b0[j]; a1[j] += b1[j]; }
    // reduce across neighbor slots: masks FGN, 2*FGN, ..., 32
#pragma unroll
    for (int m = FGN; m < 64; m <<= 1) {
#pragma unroll
      for (int j = 0; j < 4; ++j) {
        a0[j][0] += __shfl_xor(a0[j][0], m);
        a0[j][1] += __shfl_xor(a0[j][1], m);
        a1[j][0] += __shfl_xor(a1[j][0], m);
        a1[j][1] += __shfl_xor(a1[j][1], m);
      }
    }
    if (slot == 0) {
      *(float4*)&aggL[r0 * PAD + fg * 8] =
          make_float4(a0[0][0], a0[0][1], a0[1][0], a0[1][1]);
      *(float4*)&aggL[r0 * PAD + fg * 8 + 4] =
          make_float4(a0[2][0], a0[2][1], a0[3][0], a0[3][1]);
      *(float4*)&aggL[r1 * PAD + fg * 8] =
          make_float4(a1[0][0], a1[0][1], a1[1][0], a1[1][1]);
      *(float4*)&aggL[r1 * PAD + fg * 8 + 4] =
          make_float4(a1[2][0], a1[2][1], a1[3][0], a1[3][1]);
    }
  }
  __syncthreads();

  int n = tile * 64 + lane;
  if (n >= N) return;
  int wbase = w * 16;
  float accR[16], accT[16];
#pragma unroll
  for (int j = 0; j < 16; ++j) {
    accR[j] = 0.f;
    accT[j] = 0.f;
  }
#pragma unroll 2
  for (int fq = 0; fq < FIN / 4; ++fq) {
    float4 qa = *(const float4*)&aggL[lane * PAD + fq * 4];
    float4 qh = *(const float4*)&hin[(size_t)n * FIN + fq * 4];
#pragma unroll
    for (int j = 0; j < 16; ++j) {
      int o = wbase + j;
      const float* wr = &wrel[o * FIN + fq * 4];
      const float* wt = &wroot[o * FIN + fq * 4];
      accR[j] += wr[0] * qa.x + wr[1] * qa.y + wr[2] * qa.z + wr[3] * qa.w;
      accT[j] += wt[0] * qh.x + wt[1] * qh.y + wt[2] * qh.z + wt[3] * qh.w;
    }
  }
#pragma unroll
  for (int qq = 0; qq < 4; ++qq) {
    float4 rv;
    float* rr = (float*)&rv;
#pragma unroll
    for (int jj = 0; jj < 4; ++jj) {
      int j = qq * 4 + jj;
      rr[jj] = fmaxf(accR[j] + accT[j] + brel[wbase + j], 0.f);
    }
    *(float4*)&hout[(size_t)n * 64 + wbase + qq * 4] = rv;
  }
}

// ---------------- mean-pool + dense(relu) + out + softmax ----------------
__global__ void k_final(const float* __restrict__ h, const int* __restrict__ goff,
                        const float* __restrict__ dw, const float* __restrict__ db,
                        const float* __restrict__ ow, const float* __restrict__ ob,
                        float* __restrict__ out) {
  __shared__ float red[256];
  __shared__ float pl[64];
  __shared__ float gl[64];
  int g = blockIdx.x;
  int s = goff[g], e = goff[g + 1];
  int t = threadIdx.x;
  int f = t & 63, sub = t >> 6;
  float s1 = 0.f;
  for (int i = s + sub; i < e; i += 4) s1 += h[i * 64 + f];
  red[t] = s1;
  __syncthreads();
  if (t < 64) {
    float S = red[t] + red[64 + t] + red[128 + t] + red[192 + t];
    float cnt = (float)max(e - s, 1);
    pl[t] = S / cnt;
  }
  __syncthreads();
  if (t < 64) {
    float acc = db[t];
#pragma unroll 8
    for (int k = 0; k < 64; ++k) acc += dw[t * 64 + k] * pl[k];
    gl[t] = fmaxf(acc, 0.f);
  }
  __syncthreads();
  if (t == 0) {
    float l0 = ob[0], l1 = ob[1];
    for (int k = 0; k < 64; ++k) {
      l0 += ow[k] * gl[k];
      l1 += ow[64 + k] * gl[k];
    }
    float m = fmaxf(l0, l1);
    float e0 = expf(l0 - m), e1 = expf(l1 - m);
    float inv = 1.f / (e0 + e1);
    out[g * 2 + 0] = e0 * inv;
    out[g * 2 + 1] = e1 * inv;
  }
}

extern "C" void kernel_launch(void* const* d_in, const int* in_sizes, int n_in,
                              void* d_out, int out_size, void* d_ws, size_t ws_size,
                              hipStream_t stream) {
  const float* x = (const float*)d_in[0];
  const int* ei = (const int*)d_in[1];
  const int* batch = (const int*)d_in[2];
  const float* gn0_w = (const float*)d_in[3];
  const float* gn0_b = (const float*)d_in[4];
  const float* gn0_ms = (const float*)d_in[5];
  const float* gn1_w = (const float*)d_in[6];
  const float* gn1_b = (const float*)d_in[7];
  const float* gn1_ms = (const float*)d_in[8];
  const float* gn2_w = (const float*)d_in[9];
  const float* gn2_b = (const float*)d_in[10];
  const float* gn2_ms = (const float*)d_in[11];
  const float* w1_rel = (const float*)d_in[12];
  const float* b1 = (const float*)d_in[13];
  const float* w1_root = (const float*)d_in[14];
  const float* w2_rel = (const float*)d_in[15];
  const float* b2 = (const float*)d_in[16];
  const float* w2_root = (const float*)d_in[17];
  const float* w3_rel = (const float*)d_in[18];
  const float* b3 = (const float*)d_in[19];
  const float* w3_root = (const float*)d_in[20];
  const float* dense_w = (const float*)d_in[21];
  const float* dense_b = (const float*)d_in[22];
  const float* out_w = (const float*)d_in[23];
  const float* out_b = (const float*)d_in[24];

  int N = in_sizes[2];
  int E = in_sizes[1] / 2;
  int B = (N >> BSHIFT) + 1;

  char* ws = (char*)d_ws;
  auto alloc = [&](size_t bytes) {
    char* p = ws;
    ws += (bytes + 255) & ~(size_t)255;
    return p;
  };
  int* rowptr = (int*)alloc(((size_t)N + 1) * 4);
  int* goff = (int*)alloc((NG + 1) * 4);
  int* bucketCnt = (int*)alloc((size_t)B * 4);
  int* bucketOff = (int*)alloc((size_t)B * 4);
  int* bucketCur = (int*)alloc((size_t)B * 4);
  int* col = (int*)alloc((size_t)E * 4);
  size_t hbytes = (size_t)N * 64 * 4;
  size_t ebytes = (size_t)E * 4;  // u32 entries
  char* hA_raw = (char*)alloc(hbytes > ebytes ? hbytes : ebytes);  // hA aliases ebuf
  float* hA = (float*)hA_raw;
  u32* ebuf = (u32*)hA_raw;
  float* hB = (float*)alloc(hbytes);
  unsigned short* hbf = (unsigned short*)alloc((size_t)N * 64 * 2);

  const int* src = ei;
  const int* dst = ei + E;

  hipMemsetAsync(bucketCnt, 0, (size_t)B * 4, stream);
  k_bounds<<<(N + 255) / 256, 256, 0, stream>>>(batch, goff, N);
  k_hist<<<256, 256, 0, stream>>>(dst, bucketCnt, E, B);
  k_bscan<<<1, 1024, 0, stream>>>(bucketCnt, bucketOff, bucketCur, B);
  int nbs = 192;
  int C = (E + nbs - 1) / nbs;
  k_binscatter<<<nbs, 256, 0, stream>>>(src, dst, bucketCur, ebuf, E, B, C);
  k_bucket_fill<<<B, 256, 0, stream>>>(ebuf, bucketOff, rowptr, col, N, E, B);

  int tiles = (N + 63) / 64;
  k_gn<16><<<NG, 256, 0, stream>>>(x, hA, hbf, goff, gn0_w, gn0_b, gn0_ms);
  k_conv<16><<<tiles, 256, 0, stream>>>(hA, (const u32*)hbf, hB, rowptr, col, w1_rel, b1, w1_root, N);
  k_gn<64><<<NG, 256, 0, stream>>>(hB, hB, hbf, goff, gn1_w, gn1_b, gn1_ms);
  k_conv<64><<<tiles, 256, 0, stream>>>(hB, (const u32*)hbf, hA, rowptr, col, w2_rel, b2, w2_root, N);
  k_gn<64><<<NG, 256, 0, stream>>>(hA, hA, hbf, goff, gn2_w, gn2_b, gn2_ms);
  k_conv<64><<<tiles, 256, 0, stream>>>(hA, (const u32*)hbf, hB, rowptr, col, w3_rel, b3, w3_root, N);
  k_final<<<NG, 256, 0, stream>>>(hB, goff, dense_w, dense_b, out_w, out_b, (float*)d_out);
}